// Round 1
// baseline (85.133 us; speedup 1.0000x reference)
//
#include <hip/hip_runtime.h>
#include <hip/hip_bf16.h>
#include <math.h>

#define K_FINE 2048
#define NBATCH 8
#define HW 147456          // 384*384
#define N1 1179648         // 8*HW
#define IMG 384

// ws layout in 4-byte words
#define WS_MM    0                           // 6 encoded min/max (x,t,d)
#define WS_HIST  8                           // 8*2048 int counts
#define NB_HD    128
#define WS_DEPTH (WS_HIST + NBATCH*K_FINE)   // 128 float partials
#define NB_SSIM  1152
#define WS_SSIM  (WS_DEPTH + NB_HD)          // 1152 float partials
#define NB_UNIF  64
#define WS_UNIF  (WS_SSIM + NB_SSIM)         // 64 float partials

__device__ __forceinline__ unsigned fenc(float f) {
    unsigned u = __float_as_uint(f);
    return (u & 0x80000000u) ? ~u : (u | 0x80000000u);
}
__device__ __forceinline__ float fdec(unsigned e) {
    unsigned u = (e & 0x80000000u) ? (e ^ 0x80000000u) : ~e;
    return __uint_as_float(u);
}

// ---------------- init: zero hist, init min/max slots ----------------
__global__ void k_init(unsigned* __restrict__ ws) {
    int idx = blockIdx.x * 256 + threadIdx.x;
    if (idx < 6) ws[WS_MM + idx] = (idx & 1) ? 0u : 0xFFFFFFFFu;
    if (idx < NBATCH * K_FINE) ws[WS_HIST + idx] = 0u;
}

// ---------------- global min/max of 3 tensors ----------------
// grid = 3*72 blocks, each block: 16384 elems (4096 float4)
__global__ __launch_bounds__(256) void k_minmax(const float* __restrict__ x,
                                                const float* __restrict__ t,
                                                const float* __restrict__ d,
                                                unsigned* __restrict__ ws) {
    int ti  = blockIdx.x / 72;
    int blk = blockIdx.x % 72;
    const float* p = (ti == 0) ? x : ((ti == 1) ? t : d);
    const float4* p4 = (const float4*)p + blk * 4096;
    float mn = 3.4e38f, mx = -3.4e38f;
    for (int i = threadIdx.x; i < 4096; i += 256) {
        float4 v = p4[i];
        mn = fminf(mn, fminf(fminf(v.x, v.y), fminf(v.z, v.w)));
        mx = fmaxf(mx, fmaxf(fmaxf(v.x, v.y), fmaxf(v.z, v.w)));
    }
    #pragma unroll
    for (int off = 32; off; off >>= 1) {
        mn = fminf(mn, __shfl_down(mn, off, 64));
        mx = fmaxf(mx, __shfl_down(mx, off, 64));
    }
    __shared__ float smn[4], smx[4];
    if ((threadIdx.x & 63) == 0) { smn[threadIdx.x >> 6] = mn; smx[threadIdx.x >> 6] = mx; }
    __syncthreads();
    if (threadIdx.x == 0) {
        #pragma unroll
        for (int w = 1; w < 4; w++) { mn = fminf(mn, smn[w]); mx = fmaxf(mx, smx[w]); }
        atomicMin(&ws[WS_MM + ti * 2],     fenc(mn));
        atomicMax(&ws[WS_MM + ti * 2 + 1], fenc(mx));
    }
}

// ---------------- fine histogram of normalized x + depth dot ----------------
// grid = 8*16 blocks; block handles 9216 elems (2304 float4) of one batch
__global__ __launch_bounds__(256) void k_hist_depth(const float* __restrict__ x,
                                                    const float* __restrict__ d,
                                                    unsigned* __restrict__ ws) {
    __shared__ int lh[K_FINE];
    for (int i = threadIdx.x; i < K_FINE; i += 256) lh[i] = 0;
    __syncthreads();
    float xmn  = fdec(ws[0]);
    float xinv = 1.0f / (fdec(ws[1]) - xmn);
    float dmn  = fdec(ws[4]);
    float dinv = 1.0f / (fdec(ws[5]) - dmn);
    int batch = blockIdx.x >> 4;
    int blk   = blockIdx.x & 15;
    const float4* x4 = (const float4*)x + (size_t)batch * (HW / 4) + blk * 2304;
    const float4* d4 = (const float4*)d + (size_t)batch * (HW / 4) + blk * 2304;
    float dsum = 0.f;
    for (int i = threadIdx.x; i < 2304; i += 256) {
        float4 xv = x4[i], dv = d4[i];
        float o0 = (xv.x - xmn) * xinv, o1 = (xv.y - xmn) * xinv;
        float o2 = (xv.z - xmn) * xinv, o3 = (xv.w - xmn) * xinv;
        dsum += o0 * ((dv.x - dmn) * dinv) + o1 * ((dv.y - dmn) * dinv)
              + o2 * ((dv.z - dmn) * dinv) + o3 * ((dv.w - dmn) * dinv);
        int j0 = min(K_FINE - 1, max(0, (int)(o0 * K_FINE)));
        int j1 = min(K_FINE - 1, max(0, (int)(o1 * K_FINE)));
        int j2 = min(K_FINE - 1, max(0, (int)(o2 * K_FINE)));
        int j3 = min(K_FINE - 1, max(0, (int)(o3 * K_FINE)));
        atomicAdd(&lh[j0], 1); atomicAdd(&lh[j1], 1);
        atomicAdd(&lh[j2], 1); atomicAdd(&lh[j3], 1);
    }
    __syncthreads();
    int* gh = (int*)&ws[WS_HIST + batch * K_FINE];
    for (int i = threadIdx.x; i < K_FINE; i += 256)
        if (lh[i]) atomicAdd(&gh[i], lh[i]);
    // block-reduce dsum (deterministic: fixed order)
    #pragma unroll
    for (int off = 32; off; off >>= 1) dsum += __shfl_down(dsum, off, 64);
    __shared__ float sred[4];
    if ((threadIdx.x & 63) == 0) sred[threadIdx.x >> 6] = dsum;
    __syncthreads();
    if (threadIdx.x == 0)
        ((float*)ws)[WS_DEPTH + blockIdx.x] = sred[0] + sred[1] + sred[2] + sred[3];
}

// ---------------- SSIM (separable 11x11 gaussian, zero pad) ----------------
#define TS 32
#define TW 42
__global__ __launch_bounds__(256) void k_ssim(const float* __restrict__ x,
                                              const float* __restrict__ t,
                                              unsigned* __restrict__ ws) {
    __shared__ float sO[TW][TW + 2];
    __shared__ float sI[TW][TW + 2];
    __shared__ float hr0[TW][TS + 1], hr1[TW][TS + 1], hr2[TW][TS + 1],
                     hr3[TW][TS + 1], hr4[TW][TS + 1];
    // gaussian window, normalized (matches ref: exp(-k^2/(2*1.5^2)), k=-5..5)
    float g[11];
    {
        float s = 0.f;
        #pragma unroll
        for (int i = 0; i < 11; i++) {
            float dd = (float)(i - 5);
            g[i] = expf(-dd * dd / 4.5f);
            s += g[i];
        }
        float is = 1.0f / s;
        #pragma unroll
        for (int i = 0; i < 11; i++) g[i] *= is;
    }
    float xmn  = fdec(ws[0]);
    float xinv = 1.0f / (fdec(ws[1]) - xmn);
    float tmn  = fdec(ws[2]);
    float tinv = 1.0f / (fdec(ws[3]) - tmn);
    int img = blockIdx.x / 144;
    int tl  = blockIdx.x % 144;
    int ty0 = (tl / 12) * TS - 5;
    int tx0 = (tl % 12) * TS - 5;
    const float* xb = x + (size_t)img * HW;
    const float* tb = t + (size_t)img * HW;
    for (int idx = threadIdx.x; idx < TW * TW; idx += 256) {
        int r = idx / TW, c = idx % TW;
        int gy = ty0 + r, gx = tx0 + c;
        float xv = 0.f, tv = 0.f;
        if (gy >= 0 && gy < IMG && gx >= 0 && gx < IMG) {
            int o = gy * IMG + gx;
            xv = (xb[o] - xmn) * xinv;
            tv = (tb[o] - tmn) * tinv;
        }
        sO[r][c] = xv; sI[r][c] = tv;
    }
    __syncthreads();
    // horizontal pass: 5 channels
    for (int idx = threadIdx.x; idx < TW * TS; idx += 256) {
        int r = idx >> 5, cx = idx & 31;
        float so = 0, si = 0, soo = 0, sii = 0, soi = 0;
        #pragma unroll
        for (int dx = 0; dx < 11; dx++) {
            float o = sO[r][cx + dx];
            float ii = sI[r][cx + dx];
            float w = g[dx];
            so += w * o; si += w * ii;
            soo += w * o * o; sii += w * ii * ii; soi += w * o * ii;
        }
        hr0[r][cx] = so; hr1[r][cx] = si; hr2[r][cx] = soo;
        hr3[r][cx] = sii; hr4[r][cx] = soi;
    }
    __syncthreads();
    // vertical pass + SSIM formula
    const float C1 = 1e-4f, C2 = 9e-4f;
    float lsum = 0.f;
    for (int idx = threadIdx.x; idx < TS * TS; idx += 256) {
        int oy = idx >> 5, ox = idx & 31;
        float mu1 = 0, mu2 = 0, m11 = 0, m22 = 0, m12 = 0;
        #pragma unroll
        for (int dy = 0; dy < 11; dy++) {
            float w = g[dy];
            mu1 += w * hr0[oy + dy][ox];
            mu2 += w * hr1[oy + dy][ox];
            m11 += w * hr2[oy + dy][ox];
            m22 += w * hr3[oy + dy][ox];
            m12 += w * hr4[oy + dy][ox];
        }
        float mu1s = mu1 * mu1, mu2s = mu2 * mu2, mu12 = mu1 * mu2;
        float s1 = m11 - mu1s, s2 = m22 - mu2s, s12 = m12 - mu12;
        float num = (2.f * mu12 + C1) * (2.f * s12 + C2);
        float den = (mu1s + mu2s + C1) * (s1 + s2 + C2);
        lsum += num / den;
    }
    #pragma unroll
    for (int off = 32; off; off >>= 1) lsum += __shfl_down(lsum, off, 64);
    __shared__ float sred[4];
    if ((threadIdx.x & 63) == 0) sred[threadIdx.x >> 6] = lsum;
    __syncthreads();
    if (threadIdx.x == 0)
        ((float*)ws)[WS_SSIM + blockIdx.x] = sred[0] + sred[1] + sred[2] + sred[3];
}

// ---------------- soft hist from fine hist + entropy ----------------
// grid = 64: bid>>3 = batch, bid&7 = 32-bin segment; tid>>3 = local bin, tid&7 = j-slice
__global__ __launch_bounds__(256) void k_softhist(unsigned* __restrict__ ws) {
    __shared__ int lh[K_FINE];
    int batch = blockIdx.x >> 3;
    const int* gh = (const int*)&ws[WS_HIST + batch * K_FINE];
    for (int i = threadIdx.x; i < K_FINE; i += 256) lh[i] = gh[i];
    __syncthreads();
    int binLocal = threadIdx.x >> 3;
    int sub      = threadIdx.x & 7;
    int bin = (blockIdx.x & 7) * 32 + binLocal;
    const float delta = 1.0f / 256.0f;
    const float r = expf(3.0f * delta);      // e^{3*delta}
    float L = (float)bin * delta;            // left edge; contribution telescopes:
    float h = 0.f;                           // sigma(3(v-L)) - sigma(3(v-L-delta))
    for (int j = sub; j < K_FINE; j += 8) {
        float cnt = (float)lh[j];
        float v = ((float)j + 0.5f) * (1.0f / K_FINE);
        float u = expf(3.0f * (L - v));      // e^{-3(v-L)}
        float term = 1.0f / (1.0f + u) - 1.0f / (1.0f + u * r);
        h += cnt * term;
    }
    h += __shfl_down(h, 4, 8);
    h += __shfl_down(h, 2, 8);
    h += __shfl_down(h, 1, 8);
    float hl = 0.f;
    if (sub == 0) hl = (h > 0.f) ? h * logf(h) : 0.f;
    #pragma unroll
    for (int off = 32; off; off >>= 1) hl += __shfl_down(hl, off, 64);
    __shared__ float sred[4];
    if ((threadIdx.x & 63) == 0) sred[threadIdx.x >> 6] = hl;
    __syncthreads();
    if (threadIdx.x == 0)
        ((float*)ws)[WS_UNIF + blockIdx.x] = sred[0] + sred[1] + sred[2] + sred[3];
}

// ---------------- final deterministic combine ----------------
__global__ __launch_bounds__(256) void k_final(const unsigned* __restrict__ wsu,
                                               float* __restrict__ out) {
    const float* wsf = (const float*)wsu;
    int tid = threadIdx.x;
    float a = 0.f, b = 0.f, c = 0.f;
    for (int i = tid; i < NB_HD;   i += 256) a += wsf[WS_DEPTH + i];
    for (int i = tid; i < NB_SSIM; i += 256) b += wsf[WS_SSIM + i];
    for (int i = tid; i < NB_UNIF; i += 256) c += wsf[WS_UNIF + i];
    __shared__ float ra[256], rb[256], rc[256];
    ra[tid] = a; rb[tid] = b; rc[tid] = c;
    __syncthreads();
    for (int s = 128; s; s >>= 1) {
        if (tid < s) {
            ra[tid] += ra[tid + s];
            rb[tid] += rb[tid + s];
            rc[tid] += rc[tid + s];
        }
        __syncthreads();
    }
    if (tid == 0) {
        float uniform  = rc[0] / 8.0f;
        float depthL   = ra[0] / 8.0f;
        float ssimMean = rb[0] / (float)N1;
        out[0] = 1e-6f * uniform + 1e-5f * depthL + (1.0f - ssimMean);
    }
}

extern "C" void kernel_launch(void* const* d_in, const int* in_sizes, int n_in,
                              void* d_out, int out_size, void* d_ws, size_t ws_size,
                              hipStream_t stream) {
    const float* x  = (const float*)d_in[0];
    const float* tg = (const float*)d_in[1];
    const float* dp = (const float*)d_in[2];
    unsigned* ws = (unsigned*)d_ws;
    float* out = (float*)d_out;
    hipLaunchKernelGGL(k_init,       dim3(64),   dim3(256), 0, stream, ws);
    hipLaunchKernelGGL(k_minmax,     dim3(216),  dim3(256), 0, stream, x, tg, dp, ws);
    hipLaunchKernelGGL(k_hist_depth, dim3(128),  dim3(256), 0, stream, x, dp, ws);
    hipLaunchKernelGGL(k_ssim,       dim3(1152), dim3(256), 0, stream, x, tg, ws);
    hipLaunchKernelGGL(k_softhist,   dim3(64),   dim3(256), 0, stream, ws);
    hipLaunchKernelGGL(k_final,      dim3(1),    dim3(256), 0, stream, ws, out);
}

// Round 2
// 52.394 us; speedup vs baseline: 1.6249x; 1.6249x over previous
//
#include <hip/hip_runtime.h>
#include <hip/hip_bf16.h>
#include <math.h>

#define K_FINE 2048
#define NBATCH 8
#define HW 147456          // 384*384
#define N1 1179648         // 8*HW
#define IMG 384

// ws layout in 4-byte words
#define WS_MM    0                           // 6 encoded min/max (x,t,d)
#define WS_HIST  8                           // 8*2048 int counts
#define NB_HD    256
#define WS_DEPTH (WS_HIST + NBATCH*K_FINE)   // 256 float partials
#define NB_SSIM  1152
#define WS_SSIM  (WS_DEPTH + NB_HD)          // 1152 float partials
#define NB_UNIF  256
#define WS_UNIF  (WS_SSIM + NB_SSIM)         // 256 float partials

__device__ __forceinline__ unsigned fenc(float f) {
    unsigned u = __float_as_uint(f);
    return (u & 0x80000000u) ? ~u : (u | 0x80000000u);
}
__device__ __forceinline__ float fdec(unsigned e) {
    unsigned u = (e & 0x80000000u) ? (e ^ 0x80000000u) : ~e;
    return __uint_as_float(u);
}

// ---------------- init: zero hist, init min/max slots ----------------
__global__ void k_init(unsigned* __restrict__ ws) {
    int idx = blockIdx.x * 256 + threadIdx.x;
    if (idx < 6) ws[WS_MM + idx] = (idx & 1) ? 0u : 0xFFFFFFFFu;
    if (idx < NBATCH * K_FINE) ws[WS_HIST + idx] = 0u;
}

// ---------------- global min/max of 3 tensors ----------------
// grid = 3*72 blocks, each block: 16384 elems (4096 float4)
__global__ __launch_bounds__(256) void k_minmax(const float* __restrict__ x,
                                                const float* __restrict__ t,
                                                const float* __restrict__ d,
                                                unsigned* __restrict__ ws) {
    int ti  = blockIdx.x / 72;
    int blk = blockIdx.x % 72;
    const float* p = (ti == 0) ? x : ((ti == 1) ? t : d);
    const float4* p4 = (const float4*)p + blk * 4096;
    float mn = 3.4e38f, mx = -3.4e38f;
    for (int i = threadIdx.x; i < 4096; i += 256) {
        float4 v = p4[i];
        mn = fminf(mn, fminf(fminf(v.x, v.y), fminf(v.z, v.w)));
        mx = fmaxf(mx, fmaxf(fmaxf(v.x, v.y), fmaxf(v.z, v.w)));
    }
    #pragma unroll
    for (int off = 32; off; off >>= 1) {
        mn = fminf(mn, __shfl_down(mn, off, 64));
        mx = fmaxf(mx, __shfl_down(mx, off, 64));
    }
    __shared__ float smn[4], smx[4];
    if ((threadIdx.x & 63) == 0) { smn[threadIdx.x >> 6] = mn; smx[threadIdx.x >> 6] = mx; }
    __syncthreads();
    if (threadIdx.x == 0) {
        #pragma unroll
        for (int w = 1; w < 4; w++) { mn = fminf(mn, smn[w]); mx = fmaxf(mx, smx[w]); }
        atomicMin(&ws[WS_MM + ti * 2],     fenc(mn));
        atomicMax(&ws[WS_MM + ti * 2 + 1], fenc(mx));
    }
}

// ---------------- fine histogram of normalized x + depth dot ----------------
// grid = 8*32 blocks; block handles 4608 elems (1152 float4) of one batch
__global__ __launch_bounds__(256) void k_hist_depth(const float* __restrict__ x,
                                                    const float* __restrict__ d,
                                                    unsigned* __restrict__ ws) {
    __shared__ int lh[K_FINE];
    for (int i = threadIdx.x; i < K_FINE; i += 256) lh[i] = 0;
    __syncthreads();
    float xmn  = fdec(ws[0]);
    float xinv = 1.0f / (fdec(ws[1]) - xmn);
    float dmn  = fdec(ws[4]);
    float dinv = 1.0f / (fdec(ws[5]) - dmn);
    int batch = blockIdx.x >> 5;
    int blk   = blockIdx.x & 31;
    const float4* x4 = (const float4*)x + (size_t)batch * (HW / 4) + blk * 1152;
    const float4* d4 = (const float4*)d + (size_t)batch * (HW / 4) + blk * 1152;
    float dsum = 0.f;
    for (int i = threadIdx.x; i < 1152; i += 256) {
        float4 xv = x4[i], dv = d4[i];
        float o0 = (xv.x - xmn) * xinv, o1 = (xv.y - xmn) * xinv;
        float o2 = (xv.z - xmn) * xinv, o3 = (xv.w - xmn) * xinv;
        dsum += o0 * ((dv.x - dmn) * dinv) + o1 * ((dv.y - dmn) * dinv)
              + o2 * ((dv.z - dmn) * dinv) + o3 * ((dv.w - dmn) * dinv);
        int j0 = min(K_FINE - 1, max(0, (int)(o0 * K_FINE)));
        int j1 = min(K_FINE - 1, max(0, (int)(o1 * K_FINE)));
        int j2 = min(K_FINE - 1, max(0, (int)(o2 * K_FINE)));
        int j3 = min(K_FINE - 1, max(0, (int)(o3 * K_FINE)));
        atomicAdd(&lh[j0], 1); atomicAdd(&lh[j1], 1);
        atomicAdd(&lh[j2], 1); atomicAdd(&lh[j3], 1);
    }
    __syncthreads();
    int* gh = (int*)&ws[WS_HIST + batch * K_FINE];
    for (int i = threadIdx.x; i < K_FINE; i += 256)
        if (lh[i]) atomicAdd(&gh[i], lh[i]);
    // block-reduce dsum (deterministic: fixed order)
    #pragma unroll
    for (int off = 32; off; off >>= 1) dsum += __shfl_down(dsum, off, 64);
    __shared__ float sred[4];
    if ((threadIdx.x & 63) == 0) sred[threadIdx.x >> 6] = dsum;
    __syncthreads();
    if (threadIdx.x == 0)
        ((float*)ws)[WS_DEPTH + blockIdx.x] = sred[0] + sred[1] + sred[2] + sred[3];
}

// ---------------- SSIM (separable 11x11 gaussian, zero pad) ----------------
#define TS 32
#define TW 42
__global__ __launch_bounds__(256) void k_ssim(const float* __restrict__ x,
                                              const float* __restrict__ t,
                                              unsigned* __restrict__ ws) {
    __shared__ float sO[TW][TW + 2];
    __shared__ float sI[TW][TW + 2];
    __shared__ float hr0[TW][TS + 1], hr1[TW][TS + 1], hr2[TW][TS + 1],
                     hr3[TW][TS + 1], hr4[TW][TS + 1];
    // gaussian window, normalized (matches ref: exp(-k^2/(2*1.5^2)), k=-5..5)
    float g[11];
    {
        float s = 0.f;
        #pragma unroll
        for (int i = 0; i < 11; i++) {
            float dd = (float)(i - 5);
            g[i] = expf(-dd * dd / 4.5f);
            s += g[i];
        }
        float is = 1.0f / s;
        #pragma unroll
        for (int i = 0; i < 11; i++) g[i] *= is;
    }
    float xmn  = fdec(ws[0]);
    float xinv = 1.0f / (fdec(ws[1]) - xmn);
    float tmn  = fdec(ws[2]);
    float tinv = 1.0f / (fdec(ws[3]) - tmn);
    int img = blockIdx.x / 144;
    int tl  = blockIdx.x % 144;
    int ty0 = (tl / 12) * TS - 5;
    int tx0 = (tl % 12) * TS - 5;
    const float* xb = x + (size_t)img * HW;
    const float* tb = t + (size_t)img * HW;
    for (int idx = threadIdx.x; idx < TW * TW; idx += 256) {
        int r = idx / TW, c = idx % TW;
        int gy = ty0 + r, gx = tx0 + c;
        float xv = 0.f, tv = 0.f;
        if (gy >= 0 && gy < IMG && gx >= 0 && gx < IMG) {
            int o = gy * IMG + gx;
            xv = (xb[o] - xmn) * xinv;
            tv = (tb[o] - tmn) * tinv;
        }
        sO[r][c] = xv; sI[r][c] = tv;
    }
    __syncthreads();
    // horizontal pass: 5 channels
    for (int idx = threadIdx.x; idx < TW * TS; idx += 256) {
        int r = idx >> 5, cx = idx & 31;
        float so = 0, si = 0, soo = 0, sii = 0, soi = 0;
        #pragma unroll
        for (int dx = 0; dx < 11; dx++) {
            float o = sO[r][cx + dx];
            float ii = sI[r][cx + dx];
            float w = g[dx];
            so += w * o; si += w * ii;
            soo += w * o * o; sii += w * ii * ii; soi += w * o * ii;
        }
        hr0[r][cx] = so; hr1[r][cx] = si; hr2[r][cx] = soo;
        hr3[r][cx] = sii; hr4[r][cx] = soi;
    }
    __syncthreads();
    // vertical pass + SSIM formula
    const float C1 = 1e-4f, C2 = 9e-4f;
    float lsum = 0.f;
    for (int idx = threadIdx.x; idx < TS * TS; idx += 256) {
        int oy = idx >> 5, ox = idx & 31;
        float mu1 = 0, mu2 = 0, m11 = 0, m22 = 0, m12 = 0;
        #pragma unroll
        for (int dy = 0; dy < 11; dy++) {
            float w = g[dy];
            mu1 += w * hr0[oy + dy][ox];
            mu2 += w * hr1[oy + dy][ox];
            m11 += w * hr2[oy + dy][ox];
            m22 += w * hr3[oy + dy][ox];
            m12 += w * hr4[oy + dy][ox];
        }
        float mu1s = mu1 * mu1, mu2s = mu2 * mu2, mu12 = mu1 * mu2;
        float s1 = m11 - mu1s, s2 = m22 - mu2s, s12 = m12 - mu12;
        float num = (2.f * mu12 + C1) * (2.f * s12 + C2);
        float den = (mu1s + mu2s + C1) * (s1 + s2 + C2);
        lsum += num / den;
    }
    #pragma unroll
    for (int off = 32; off; off >>= 1) lsum += __shfl_down(lsum, off, 64);
    __shared__ float sred[4];
    if ((threadIdx.x & 63) == 0) sred[threadIdx.x >> 6] = lsum;
    __syncthreads();
    if (threadIdx.x == 0)
        ((float*)ws)[WS_SSIM + blockIdx.x] = sred[0] + sred[1] + sred[2] + sred[3];
}

// ---------------- soft hist from fine hist + entropy ----------------
// grid = 256: bid>>5 = batch, bid&31 = 8-bin segment
// 256 threads: tid>>5 = local bin (8), tid&31 = j-slice (32)
// Key optimization: u_j = e^{3(L - v_j)} follows a geometric recurrence in j
// (one fmul per iter replaces expf), and the sigmoid difference
// 1/(1+u) - 1/(1+ur) = u(r-1)/((1+u)(1+ur)) needs only ONE approx-rcp.
__global__ __launch_bounds__(256) void k_softhist(unsigned* __restrict__ ws) {
    __shared__ int lh[K_FINE];
    int batch = blockIdx.x >> 5;
    const int* gh = (const int*)&ws[WS_HIST + batch * K_FINE];
    for (int i = threadIdx.x; i < K_FINE; i += 256) lh[i] = gh[i];
    __syncthreads();
    int binLocal = threadIdx.x >> 5;          // 0..7
    int slice    = threadIdx.x & 31;          // 0..31
    int bin = (blockIdx.x & 31) * 8 + binLocal;
    const float delta = 1.0f / 256.0f;
    const float r   = expf(3.0f * delta);     // e^{3 delta}
    const float rm1 = r - 1.0f;
    const float c32 = expf(-3.0f * 32.0f / (float)K_FINE);  // step j += 32
    float L = (float)bin * delta;
    float u = expf(3.0f * (L - ((float)slice + 0.5f) * (1.0f / K_FINE)));
    float h = 0.f;
    #pragma unroll 4
    for (int j = slice; j < K_FINE; j += 32) {
        float cnt = (float)lh[j];
        float t1  = 1.0f + u;
        float t2  = fmaf(u, r, 1.0f);
        float num = u * rm1;
        h = fmaf(cnt * num, __builtin_amdgcn_rcpf(t1 * t2), h);
        u *= c32;
    }
    // reduce over 32 slices (aligned 32-lane groups)
    #pragma unroll
    for (int off = 16; off; off >>= 1) h += __shfl_down(h, off, 32);
    __shared__ float s8[8];
    if (slice == 0) s8[binLocal] = (h > 0.f) ? h * logf(h) : 0.f;
    __syncthreads();
    if (threadIdx.x == 0) {
        float hl = 0.f;
        #pragma unroll
        for (int b = 0; b < 8; b++) hl += s8[b];
        ((float*)ws)[WS_UNIF + blockIdx.x] = hl;
    }
}

// ---------------- final deterministic combine ----------------
__global__ __launch_bounds__(256) void k_final(const unsigned* __restrict__ wsu,
                                               float* __restrict__ out) {
    const float* wsf = (const float*)wsu;
    int tid = threadIdx.x;
    float a = 0.f, b = 0.f, c = 0.f;
    for (int i = tid; i < NB_HD;   i += 256) a += wsf[WS_DEPTH + i];
    for (int i = tid; i < NB_SSIM; i += 256) b += wsf[WS_SSIM + i];
    for (int i = tid; i < NB_UNIF; i += 256) c += wsf[WS_UNIF + i];
    __shared__ float ra[256], rb[256], rc[256];
    ra[tid] = a; rb[tid] = b; rc[tid] = c;
    __syncthreads();
    for (int s = 128; s; s >>= 1) {
        if (tid < s) {
            ra[tid] += ra[tid + s];
            rb[tid] += rb[tid + s];
            rc[tid] += rc[tid + s];
        }
        __syncthreads();
    }
    if (tid == 0) {
        float uniform  = rc[0] / 8.0f;
        float depthL   = ra[0] / 8.0f;
        float ssimMean = rb[0] / (float)N1;
        out[0] = 1e-6f * uniform + 1e-5f * depthL + (1.0f - ssimMean);
    }
}

extern "C" void kernel_launch(void* const* d_in, const int* in_sizes, int n_in,
                              void* d_out, int out_size, void* d_ws, size_t ws_size,
                              hipStream_t stream) {
    const float* x  = (const float*)d_in[0];
    const float* tg = (const float*)d_in[1];
    const float* dp = (const float*)d_in[2];
    unsigned* ws = (unsigned*)d_ws;
    float* out = (float*)d_out;
    hipLaunchKernelGGL(k_init,       dim3(64),   dim3(256), 0, stream, ws);
    hipLaunchKernelGGL(k_minmax,     dim3(216),  dim3(256), 0, stream, x, tg, dp, ws);
    hipLaunchKernelGGL(k_hist_depth, dim3(256),  dim3(256), 0, stream, x, dp, ws);
    hipLaunchKernelGGL(k_ssim,       dim3(1152), dim3(256), 0, stream, x, tg, ws);
    hipLaunchKernelGGL(k_softhist,   dim3(256),  dim3(256), 0, stream, ws);
    hipLaunchKernelGGL(k_final,      dim3(1),    dim3(256), 0, stream, ws, out);
}